// Round 4
// baseline (260.366 us; speedup 1.0000x reference)
//
#include <hip/hip_runtime.h>

// TripletLoss with per-class margins — fused single-kernel version.
// d_ap = ||a - p + 1e-6||_2, d_an = ||a - n + 1e-6||_2
// loss = mean(relu(d_ap - d_an + margin[cs]))
//
// Round 3:
//  - R2 memory structure kept (32 lanes/row, coalesced float4, depth-1 prefetch)
//  - split shuffle-reduce: dap -> even lanes, dan -> odd lanes, one shared
//    butterfly (7 DS ops/row instead of 10)
//  - fused final reduction: last-finishing block sums the 2048 partials in
//    fixed index order (deterministic), saving the second kernel launch.

#define TL_D 128
#define TL_BLOCK 256
#define TL_GRID 2048

__device__ __forceinline__ float tl_margin(int c) {
    return (c == 0) ? 0.10f
         : (c == 1) ? 0.085f
         : (c == 2) ? 0.07f
         : 0.04f;
}

#define TL_ACC(av, bv, dst)                           \
    {                                                 \
        float _d;                                     \
        _d = (av).x - (bv).x + 1e-6f; dst += _d * _d; \
        _d = (av).y - (bv).y + 1e-6f; dst += _d * _d; \
        _d = (av).z - (bv).z + 1e-6f; dst += _d * _d; \
        _d = (av).w - (bv).w + 1e-6f; dst += _d * _d; \
    }

__global__ __launch_bounds__(TL_BLOCK) void triplet_fused_kernel(
    const float* __restrict__ a,
    const float* __restrict__ p,
    const float* __restrict__ n,
    const int* __restrict__ cs32,      // low 32-bit words of the int64 cs array
    float* __restrict__ partials,      // [gridDim.x] in d_ws
    unsigned int* __restrict__ counter,// 1 uint in d_ws, zeroed before launch
    float* __restrict__ out,
    int nrows, float invB)
{
    const int tid    = threadIdx.x;
    const int lane32 = tid & 31;
    const int G      = blockIdx.x * (TL_BLOCK / 32) + (tid >> 5);
    const int TG     = gridDim.x * (TL_BLOCK / 32);

    float local = 0.0f;

    int row = G;
    float4 aC, pC, nC;
    int cC = 0;
    if (row < nrows) {
        const size_t base = (size_t)row * TL_D + lane32 * 4;
        aC = *reinterpret_cast<const float4*>(a + base);
        pC = *reinterpret_cast<const float4*>(p + base);
        nC = *reinterpret_cast<const float4*>(n + base);
        cC = cs32[2 * (size_t)row];
    }

    while (row < nrows) {
        // ---- prefetch next iteration (branch-free, clamped row) ----
        const int nrow = row + TG;
        const int lrow = (nrow < nrows) ? nrow : row;
        const size_t nb = (size_t)lrow * TL_D + lane32 * 4;
        const float4 aN = *reinterpret_cast<const float4*>(a + nb);
        const float4 pN = *reinterpret_cast<const float4*>(p + nb);
        const float4 nN = *reinterpret_cast<const float4*>(n + nb);
        const int    cN = cs32[2 * (size_t)lrow];

        // ---- compute current iteration ----
        float dap = 0.0f, dan = 0.0f;
        TL_ACC(aC, pC, dap);
        TL_ACC(aC, nC, dan);

        // Split reduce: pair-combine so even lanes carry dap, odd lanes dan,
        // then one butterfly reduces both simultaneously.
        const float od = __shfl_xor(dap, 1, 64);
        const float on = __shfl_xor(dan, 1, 64);
        float v = (lane32 & 1) ? (dan + on) : (dap + od);
        #pragma unroll
        for (int m = 2; m <= 16; m <<= 1) v += __shfl_xor(v, m, 64);
        // lane 0: full dap, lane 1: full dan
        const float sq = sqrtf(v);
        const float other = __shfl_xor(sq, 1, 64);
        if (lane32 == 0) {
            local += fmaxf(sq - other + tl_margin(cC), 0.0f);
        }

        // ---- rotate ----
        row = nrow;
        aC = aN; pC = pN; nC = nN; cC = cN;
    }

    // Cross-group combine within the wave (only lanes 0 and 32 are nonzero).
    local += __shfl_xor(local, 32, 64);

    __shared__ float swave[TL_BLOCK / 64];
    __shared__ int sIsLast;
    if ((tid & 63) == 0) swave[tid >> 6] = local;
    __syncthreads();
    if (tid == 0) {
        float s = 0.0f;
        #pragma unroll
        for (int w = 0; w < TL_BLOCK / 64; ++w) s += swave[w];
        partials[blockIdx.x] = s;
        __threadfence();  // release: make partial visible device-wide
        const unsigned int prev =
            __hip_atomic_fetch_add(counter, 1u, __ATOMIC_ACQ_REL,
                                   __HIP_MEMORY_SCOPE_AGENT);
        sIsLast = (prev == gridDim.x - 1) ? 1 : 0;
    }
    __syncthreads();

    if (sIsLast) {
        __threadfence();  // acquire: see all blocks' partials
        float s = 0.0f;
        for (int i = tid; i < (int)gridDim.x; i += TL_BLOCK) s += partials[i];
        __shared__ float sdata[TL_BLOCK];
        sdata[tid] = s;
        __syncthreads();
        #pragma unroll
        for (int st = TL_BLOCK / 2; st > 0; st >>= 1) {
            if (tid < st) sdata[tid] += sdata[tid + st];
            __syncthreads();
        }
        if (tid == 0) out[0] = sdata[0] * invB;
    }
}

extern "C" void kernel_launch(void* const* d_in, const int* in_sizes, int n_in,
                              void* d_out, int out_size, void* d_ws, size_t ws_size,
                              hipStream_t stream)
{
    const float* a    = (const float*)d_in[0];
    const float* p    = (const float*)d_in[1];
    const float* n    = (const float*)d_in[2];
    const int*   cs32 = (const int*)d_in[3];   // int64 cs, values 0..3 -> low words
    float*       out  = (float*)d_out;

    const int nrows = in_sizes[3];  // B = 262144

    float* partials = (float*)d_ws;
    unsigned int* counter = (unsigned int*)((char*)d_ws + TL_GRID * sizeof(float));

    int nblocks = TL_GRID;
    const int maxParts = (int)((ws_size - sizeof(unsigned int)) / sizeof(float));
    if (nblocks > maxParts) nblocks = maxParts;
    if (nblocks < 1) nblocks = 1;

    // Zero the completion counter (graph-capture legal).
    hipMemsetAsync((void*)counter, 0, sizeof(unsigned int), stream);

    triplet_fused_kernel<<<nblocks, TL_BLOCK, 0, stream>>>(
        a, p, n, cs32, partials, counter, out, nrows, 1.0f / (float)nrows);
}

// Round 5
// 77.416 us; speedup vs baseline: 3.3632x; 3.3632x over previous
//
#include <hip/hip_runtime.h>

// TripletLoss with per-class margins.
// d_ap = ||a - p + 1e-6||_2, d_an = ||a - n + 1e-6||_2
// loss = mean(relu(d_ap - d_an + margin[cs]))
//
// Round 4: revert R3's fused last-block reduction (device-scope fences emit
// L2-wide writeback/invalidate per block -> +180us). Back to the two-kernel
// R2 structure (32 lanes/row, coalesced float4, depth-1 prefetch), keeping
// R3's split butterfly reduce (7 DS ops + 1 sqrt-exchange instead of 10 DS
// ops + 2 sqrt on lane 0).

#define TL_D 128
#define TL_BLOCK 256
#define TL_GRID 2048

__device__ __forceinline__ float tl_margin(int c) {
    return (c == 0) ? 0.10f
         : (c == 1) ? 0.085f
         : (c == 2) ? 0.07f
         : 0.04f;
}

#define TL_ACC(av, bv, dst)                           \
    {                                                 \
        float _d;                                     \
        _d = (av).x - (bv).x + 1e-6f; dst += _d * _d; \
        _d = (av).y - (bv).y + 1e-6f; dst += _d * _d; \
        _d = (av).z - (bv).z + 1e-6f; dst += _d * _d; \
        _d = (av).w - (bv).w + 1e-6f; dst += _d * _d; \
    }

__global__ __launch_bounds__(TL_BLOCK) void triplet_partial_kernel(
    const float* __restrict__ a,
    const float* __restrict__ p,
    const float* __restrict__ n,
    const int* __restrict__ cs32,   // low 32-bit words of the int64 cs array
    float* __restrict__ partials,
    int nrows)
{
    const int tid    = threadIdx.x;
    const int lane32 = tid & 31;
    const int G      = blockIdx.x * (TL_BLOCK / 32) + (tid >> 5);
    const int TG     = gridDim.x * (TL_BLOCK / 32);

    float local = 0.0f;

    int row = G;
    float4 aC, pC, nC;
    int cC = 0;
    if (row < nrows) {
        const size_t base = (size_t)row * TL_D + lane32 * 4;
        aC = *reinterpret_cast<const float4*>(a + base);
        pC = *reinterpret_cast<const float4*>(p + base);
        nC = *reinterpret_cast<const float4*>(n + base);
        cC = cs32[2 * (size_t)row];
    }

    while (row < nrows) {
        // ---- prefetch next iteration (branch-free, clamped row) ----
        const int nrow = row + TG;
        const int lrow = (nrow < nrows) ? nrow : row;   // stays in bounds
        const size_t nb = (size_t)lrow * TL_D + lane32 * 4;
        const float4 aN = *reinterpret_cast<const float4*>(a + nb);
        const float4 pN = *reinterpret_cast<const float4*>(p + nb);
        const float4 nN = *reinterpret_cast<const float4*>(n + nb);
        const int    cN = cs32[2 * (size_t)lrow];

        // ---- compute current iteration ----
        float dap = 0.0f, dan = 0.0f;
        TL_ACC(aC, pC, dap);
        TL_ACC(aC, nC, dan);

        // Split reduce: pair-combine so even lanes carry dap, odd lanes dan,
        // then one butterfly reduces both simultaneously.
        const float od = __shfl_xor(dap, 1, 64);
        const float on = __shfl_xor(dan, 1, 64);
        float v = (lane32 & 1) ? (dan + on) : (dap + od);
        #pragma unroll
        for (int m = 2; m <= 16; m <<= 1) v += __shfl_xor(v, m, 64);
        // lane 0 holds full dap, lane 1 holds full dan
        const float sq = sqrtf(v);
        const float other = __shfl_xor(sq, 1, 64);
        if (lane32 == 0) {
            local += fmaxf(sq - other + tl_margin(cC), 0.0f);
        }

        // ---- rotate (vmcnt wait lands here, after the shuffles) ----
        row = nrow;
        aC = aN; pC = pN; nC = nN; cC = cN;
    }

    // Cross-group combine within the wave (only lanes 0 and 32 are nonzero).
    local += __shfl_xor(local, 32, 64);

    __shared__ float swave[TL_BLOCK / 64];
    if ((tid & 63) == 0) swave[tid >> 6] = local;
    __syncthreads();
    if (tid == 0) {
        float s = 0.0f;
        #pragma unroll
        for (int w = 0; w < TL_BLOCK / 64; ++w) s += swave[w];
        partials[blockIdx.x] = s;
    }
}

__global__ __launch_bounds__(TL_BLOCK) void triplet_final_kernel(
    const float* __restrict__ partials,
    int nparts,
    float* __restrict__ out,
    float invB)
{
    __shared__ float sdata[TL_BLOCK];
    float local = 0.0f;
    for (int i = threadIdx.x; i < nparts; i += TL_BLOCK) local += partials[i];
    sdata[threadIdx.x] = local;
    __syncthreads();
    #pragma unroll
    for (int s = TL_BLOCK / 2; s > 0; s >>= 1) {
        if (threadIdx.x < s) sdata[threadIdx.x] += sdata[threadIdx.x + s];
        __syncthreads();
    }
    if (threadIdx.x == 0) out[0] = sdata[0] * invB;
}

extern "C" void kernel_launch(void* const* d_in, const int* in_sizes, int n_in,
                              void* d_out, int out_size, void* d_ws, size_t ws_size,
                              hipStream_t stream)
{
    const float* a    = (const float*)d_in[0];
    const float* p    = (const float*)d_in[1];
    const float* n    = (const float*)d_in[2];
    const int*   cs32 = (const int*)d_in[3];   // int64 cs, values 0..3 -> low words
    float*       out  = (float*)d_out;
    float*       partials = (float*)d_ws;

    const int nrows = in_sizes[3];  // B = 262144

    int nblocks = TL_GRID;
    const int maxParts = (int)(ws_size / sizeof(float));
    if (nblocks > maxParts) nblocks = maxParts;
    if (nblocks < 1) nblocks = 1;

    triplet_partial_kernel<<<nblocks, TL_BLOCK, 0, stream>>>(a, p, n, cs32, partials, nrows);
    triplet_final_kernel<<<1, TL_BLOCK, 0, stream>>>(partials, nblocks, out, 1.0f / (float)nrows);
}